// Round 12
// baseline (250.176 us; speedup 1.0000x reference)
//
#include <hip/hip_runtime.h>
#include <math.h>

namespace {
constexpr int B = 2;
constexpr int N = 2048;
constexpr int DIM = 512;
constexpr int H = 8;
constexpr int MEM = 16;
constexpr int J = MEM + N;       // 2064
constexpr int CHUNK = 256;
constexpr int CMAX = 9;          // ceil(2064/256)
constexpr int NSLOT = 584;       // sum_t ceil((16t+32)/256) per batch
constexpr float S2 = 0.125f * 1.4426950408889634f;  // SCALE * log2(e)
// e-buffer: per b, sum_t (16t+32) j-rows * 16 i * 8 h1 bf16 elems
constexpr size_t EPB = 17170432;        // 134144 * 128
}

typedef __attribute__((ext_vector_type(8))) short short8;
typedef __attribute__((ext_vector_type(4))) float floatx4;
typedef __attribute__((ext_vector_type(4))) unsigned short ushortx4;
typedef __attribute__((ext_vector_type(8))) unsigned short ushortx8;

__device__ inline unsigned short f2bf(float f) {
    unsigned int u = __float_as_uint(f);
    u += 0x7fffu + ((u >> 16) & 1u);   // RNE
    return (unsigned short)(u >> 16);
}
__device__ inline unsigned int pk2bf(float a, float b) {
    return ((__float_as_uint(a) + 0x8000u) >> 16) |
           ((__float_as_uint(b) + 0x8000u) & 0xffff0000u);
}

// ---------------- P1: W [k][n] fp32 -> WT [n][k] bf16 (4 matrices) --------
__global__ __launch_bounds__(256)
void wt_conv(const float* __restrict__ Wq, const float* __restrict__ Wk,
             const float* __restrict__ Wv, const float* __restrict__ Wo,
             unsigned short* __restrict__ tq, unsigned short* __restrict__ tk,
             unsigned short* __restrict__ tv, unsigned short* __restrict__ to_)
{
    const int z = blockIdx.z;
    const float* __restrict__ W = (z == 0) ? Wq : (z == 1) ? Wk : (z == 2) ? Wv : Wo;
    unsigned short* __restrict__ WT = (z == 0) ? tq : (z == 1) ? tk : (z == 2) ? tv : to_;
    const int k0 = blockIdx.x * 64, n0 = blockIdx.y * 64;

    __shared__ __align__(16) unsigned short tile[64][72];
    const int t = threadIdx.x;
    const int rrow = t >> 4, rcol = (t & 15) * 4;
#pragma unroll
    for (int rr = 0; rr < 4; ++rr) {
        const int row = rrow + rr * 16;
        const float4 v = *(const float4*)(W + (size_t)(k0 + row) * DIM + n0 + rcol);
        tile[rcol + 0][row] = f2bf(v.x);
        tile[rcol + 1][row] = f2bf(v.y);
        tile[rcol + 2][row] = f2bf(v.z);
        tile[rcol + 3][row] = f2bf(v.w);
    }
    __syncthreads();
    const int orow = t >> 2, oseg = (t & 3) * 16;
    *(ushortx8*)(WT + (size_t)(n0 + orow) * DIM + k0 + oseg) =
        *(const ushortx8*)(&tile[orow][oseg]);
    *(ushortx8*)(WT + (size_t)(n0 + orow) * DIM + k0 + oseg + 8) =
        *(const ushortx8*)(&tile[orow][oseg + 8]);
}

// ---------------- K1: QKV projection GEMM (LDS double-buffered, bf16 MFMA)
__global__ __launch_bounds__(256)
void qkv_gemm(const float* __restrict__ x, const unsigned short* __restrict__ tq,
              const unsigned short* __restrict__ tk, const unsigned short* __restrict__ tv,
              unsigned short* __restrict__ q16, unsigned short* __restrict__ k16,
              unsigned short* __restrict__ vt16)
{
    const int which = blockIdx.z;
    const unsigned short* __restrict__ WT = (which == 0) ? tq : (which == 1) ? tk : tv;
    const int t = threadIdx.x;
    const int lane = t & 63, w = t >> 6;
    const int iL = lane & 15, quad = lane >> 4;
    const int mb = blockIdx.x * 64;
    const int n0 = blockIdx.y * 64;

    __shared__ __align__(16) unsigned short As[2][64][32];  // 8 KB
    __shared__ __align__(16) unsigned short Bs[2][64][32];  // 8 KB

    const int ar0 = t >> 3, as4 = (t & 7) * 4;
    const int br0 = t >> 2, bs8 = (t & 3) * 8;

    floatx4 acc[4];
#pragma unroll
    for (int ng = 0; ng < 4; ++ng) acc[ng] = (floatx4){0.f, 0.f, 0.f, 0.f};

    {
        const float4 v0 = *(const float4*)(x + (size_t)(mb + ar0) * DIM + as4);
        const float4 v1 = *(const float4*)(x + (size_t)(mb + ar0 + 32) * DIM + as4);
        ushortx4 o0 = { f2bf(v0.x), f2bf(v0.y), f2bf(v0.z), f2bf(v0.w) };
        ushortx4 o1 = { f2bf(v1.x), f2bf(v1.y), f2bf(v1.z), f2bf(v1.w) };
        *(ushortx4*)(&As[0][ar0][as4]) = o0;
        *(ushortx4*)(&As[0][ar0 + 32][as4]) = o1;
        *(ushortx8*)(&Bs[0][br0][bs8]) =
            *(const ushortx8*)(WT + (size_t)(n0 + br0) * DIM + bs8);
    }
    __syncthreads();

#pragma unroll
    for (int it = 0; it < 16; ++it) {
        const int buf = it & 1;
        if (it + 1 < 16) {
            const int k0 = (it + 1) * 32;
            const float4 v0 = *(const float4*)(x + (size_t)(mb + ar0) * DIM + k0 + as4);
            const float4 v1 = *(const float4*)(x + (size_t)(mb + ar0 + 32) * DIM + k0 + as4);
            const ushortx8 bv =
                *(const ushortx8*)(WT + (size_t)(n0 + br0) * DIM + k0 + bs8);
            ushortx4 o0 = { f2bf(v0.x), f2bf(v0.y), f2bf(v0.z), f2bf(v0.w) };
            ushortx4 o1 = { f2bf(v1.x), f2bf(v1.y), f2bf(v1.z), f2bf(v1.w) };
            *(ushortx4*)(&As[buf ^ 1][ar0][as4]) = o0;
            *(ushortx4*)(&As[buf ^ 1][ar0 + 32][as4]) = o1;
            *(ushortx8*)(&Bs[buf ^ 1][br0][bs8]) = bv;
        }
        const short8 af = *(const short8*)(&As[buf][w * 16 + iL][quad * 8]);
#pragma unroll
        for (int ng = 0; ng < 4; ++ng) {
            const short8 bf = *(const short8*)(&Bs[buf][ng * 16 + iL][quad * 8]);
            acc[ng] = __builtin_amdgcn_mfma_f32_16x16x32_bf16(af, bf, acc[ng], 0, 0, 0);
        }
        __syncthreads();
    }

    const int mbw = mb + w * 16;
    const int h0 = n0 >> 6;
    if (which == 2) {
#pragma unroll
        for (int ng = 0; ng < 4; ++ng) {
            const int d = ng * 16 + iL;
#pragma unroll
            for (int r = 0; r < 4; ++r) {
                const int m = mbw + quad * 4 + r;
                const int bb = m >> 11, ii = m & (N - 1);
                vt16[((size_t)(bb * H + h0) * 64 + d) * J + MEM + ii] = f2bf(acc[ng][r]);
            }
        }
    } else {
        unsigned short* dst = (which == 0) ? q16 : k16;
#pragma unroll
        for (int ng = 0; ng < 4; ++ng) {
            const int d = ng * 16 + iL;
#pragma unroll
            for (int r = 0; r < 4; ++r) {
                const int m = mbw + quad * 4 + r;
                const int bb = m >> 11, ii = m & (N - 1);
                const size_t rowbase = (which == 0)
                    ? ((size_t)(bb * H + h0) * N + ii)
                    : ((size_t)(bb * H + h0) * J + MEM + ii);
                dst[rowbase * 64 + d] = f2bf(acc[ng][r]);
            }
        }
    }
}

// ---------------- K1b: mem_k/mem_v into k16 rows / vt16 cols 0..15 --------
__global__ void memkv_copy(const float* __restrict__ mem_k, const float* __restrict__ mem_v,
                           unsigned short* __restrict__ k16, unsigned short* __restrict__ vt16)
{
    const int idx = blockIdx.x * 256 + threadIdx.x;  // H*MEM*64 = 8192
    if (idx >= H * MEM * 64) return;
    const int h0 = idx >> 10;
    const int rd = idx & 1023;
    const int r = rd >> 6, d = rd & 63;
    const unsigned short kk = f2bf(mem_k[idx]);
    const unsigned short vv = f2bf(mem_v[idx]);
#pragma unroll
    for (int bb = 0; bb < B; ++bb) {
        k16[((size_t)(bb * H + h0) * J + r) * 64 + d] = kk;
        vt16[((size_t)(bb * H + h0) * 64 + d) * J + r] = vv;
    }
}

// ---------------- K2a: scores pass — QK + premix + exp; store e; sum l ----
__global__ __launch_bounds__(256)
void attn_scores(const unsigned short* __restrict__ qb, const unsigned short* __restrict__ kb,
                 const float* __restrict__ prep, float* __restrict__ lbuf,
                 unsigned short* __restrict__ e16)
{
    const int c = blockIdx.x, tt = 127 - blockIdx.y, b = blockIdx.z;
    const int i0 = tt * 16;
    const int jlim = i0 + 32;
    const int jstart = c * CHUNK;
    if (jstart >= jlim) return;
    const int jend = min(jstart + CHUNK, jlim);

    __shared__ __align__(16) unsigned short q_s[8][16][64];  // 16 KB
    __shared__ __align__(16) float pre_s[64];
    const int t = threadIdx.x;
    if (t < 64) pre_s[t] = prep[t];
#pragma unroll
    for (int u4 = 0; u4 < 4; ++u4) {
        const int u = t + u4 * 256;
        const int h = u >> 7, rem = u & 127, i = rem >> 3, seg = (rem & 7) * 8;
        *(ushortx8*)(&q_s[h][i][seg]) =
            *(const ushortx8*)(qb + ((size_t)(b * H + h) * N + i0 + i) * 64 + seg);
    }
    __syncthreads();

    const int lane = t & 63, w = t >> 6;
    const int iL = lane & 15, quad = lane >> 4;
    const int i = i0 + iL;
    const size_t ebase = (size_t)b * EPB + (size_t)(8 * tt * tt + 24 * tt) * 128;

    float l_acc[8];
#pragma unroll
    for (int h1 = 0; h1 < 8; ++h1) l_acc[h1] = 0.f;

    bool any = false;
    for (int j0 = jstart + w * 16; j0 < jend; j0 += 64) {
        any = true;
        float dots[8][4];
#pragma unroll
        for (int h1 = 0; h1 < 8; ++h1)
#pragma unroll
            for (int r = 0; r < 4; ++r) dots[h1][r] = 0.f;

        const unsigned short* kp0 = kb + ((size_t)(b * H) * J + j0 + iL) * 64 + quad * 8;
        short8 kc0 = *(const short8*)kp0;
        short8 kc1 = *(const short8*)(kp0 + 32);
#pragma unroll
        for (int h0 = 0; h0 < 8; ++h0) {
            short8 kn0, kn1;
            if (h0 < 7) {
                const unsigned short* kpn =
                    kb + ((size_t)(b * H + h0 + 1) * J + j0 + iL) * 64 + quad * 8;
                kn0 = *(const short8*)kpn;
                kn1 = *(const short8*)(kpn + 32);
            }
            const short8 qf0 = *(const short8*)(&q_s[h0][iL][quad * 8]);
            const short8 qf1 = *(const short8*)(&q_s[h0][iL][quad * 8 + 32]);
            floatx4 a = {0.f, 0.f, 0.f, 0.f};
            a = __builtin_amdgcn_mfma_f32_16x16x32_bf16(kc0, qf0, a, 0, 0, 0);
            a = __builtin_amdgcn_mfma_f32_16x16x32_bf16(kc1, qf1, a, 0, 0, 0);
            const float4 pr0 = *(const float4*)(&pre_s[h0 * 8]);
            const float4 pr1 = *(const float4*)(&pre_s[h0 * 8 + 4]);
#pragma unroll
            for (int r = 0; r < 4; ++r) {
                const float av = a[r];
                dots[0][r] = fmaf(av, pr0.x, dots[0][r]);
                dots[1][r] = fmaf(av, pr0.y, dots[1][r]);
                dots[2][r] = fmaf(av, pr0.z, dots[2][r]);
                dots[3][r] = fmaf(av, pr0.w, dots[3][r]);
                dots[4][r] = fmaf(av, pr1.x, dots[4][r]);
                dots[5][r] = fmaf(av, pr1.y, dots[5][r]);
                dots[6][r] = fmaf(av, pr1.z, dots[6][r]);
                dots[7][r] = fmaf(av, pr1.w, dots[7][r]);
            }
            kc0 = kn0; kc1 = kn1;
        }

        unsigned int epk[4][4];
        float etmp[4];
#pragma unroll
        for (int h1 = 0; h1 < 8; ++h1) {
            const float slopeE = 1.4426950408889634f / (float)(2 << h1);
#pragma unroll
            for (int r = 0; r < 4; ++r) {
                const int j = j0 + quad * 4 + r;
                const bool vis = (j - MEM) <= i;
                const float e = vis ? exp2f(fmaf(dots[h1][r], S2, slopeE * (float)(j - i - MEM)))
                                    : 0.f;
                l_acc[h1] += e;
                if (h1 & 1) epk[r][h1 >> 1] = pk2bf(etmp[r], e);
                else        etmp[r] = e;
            }
        }
#pragma unroll
        for (int r = 0; r < 4; ++r) {
            uint4 o = make_uint4(epk[r][0], epk[r][1], epk[r][2], epk[r][3]);
            *(uint4*)(e16 + ebase + (size_t)((j0 + quad * 4 + r) * 16 + iL) * 8) = o;
        }
    }

#pragma unroll
    for (int h1 = 0; h1 < 8; ++h1) {
        float v = l_acc[h1];
        v += __shfl_xor(v, 16);
        v += __shfl_xor(v, 32);
        if (quad == 0 && any)
            atomicAdd(lbuf + ((size_t)(b * 128 + tt) * 8 + h1) * 16 + iL, v);
    }
}

// ---------------- K2b (atomic fallback): pv pass -------------------------
__global__ __launch_bounds__(256)
void attn_pv2(const unsigned short* __restrict__ e16, const unsigned short* __restrict__ vt,
              const float* __restrict__ postp, const float* __restrict__ hsp,
              const float* __restrict__ lbuf, float* __restrict__ ao)
{
    const int c = blockIdx.x, tt = 127 - blockIdx.y, b = blockIdx.z;
    const int i0 = tt * 16;
    const int jlim = i0 + 32;
    const int jstart = c * CHUNK;
    if (jstart >= jlim) return;
    const int jend = min(jstart + CHUNK, jlim);
    const int nw = (jend - jstart + 31) >> 5;

    __shared__ __align__(16) unsigned short p2s[2][8][16][40];
    __shared__ __align__(16) float post_s[64];

    const int t = threadIdx.x;
    if (t < 64) post_s[t] = postp[t] * hsp[t & 7];

    const int lane = t & 63, w = t >> 6;
    const int iL = lane & 15, quad = lane >> 4;
    const int dW = w * 16 + iL;
    const int i_p = t & 15;
    const int jj = t >> 4;
    const size_t ebase = (size_t)b * EPB + (size_t)(8 * tt * tt + 24 * tt) * 128;

    float linv[8];
#pragma unroll
    for (int h1 = 0; h1 < 8; ++h1)
        linv[h1] = 1.0f / lbuf[((size_t)(b * 128 + tt) * 8 + h1) * 16 + i_p];

    floatx4 y[8];
#pragma unroll
    for (int h2 = 0; h2 < 8; ++h2) y[h2] = (floatx4){0.f, 0.f, 0.f, 0.f};

    ushortx8 evc[2], evn[2];
    {
        const int j0c = jstart + jj * 2;
        const int ja = min(j0c, jend - 1), jb2 = min(j0c + 1, jend - 1);
        evc[0] = *(const ushortx8*)(e16 + ebase + (size_t)(ja * 16 + i_p) * 8);
        evc[1] = *(const ushortx8*)(e16 + ebase + (size_t)(jb2 * 16 + i_p) * 8);
    }
    __syncthreads();

    for (int n = 0; n < nw; ++n) {
        const int jw0 = jstart + n * 32;
        {
            const int j0n = jstart + (n + 1) * 32 + jj * 2;
            const int ja = min(j0n, jend - 1), jb2 = min(j0n + 1, jend - 1);
            evn[0] = *(const ushortx8*)(e16 + ebase + (size_t)(ja * 16 + i_p) * 8);
            evn[1] = *(const ushortx8*)(e16 + ebase + (size_t)(jb2 * 16 + i_p) * 8);
        }
        float p2[2][8];
#pragma unroll
        for (int s = 0; s < 2; ++s) {
#pragma unroll
            for (int h2 = 0; h2 < 8; ++h2) p2[s][h2] = 0.f;
            const int j = jw0 + jj * 2 + s;
            if (j < jend) {
#pragma unroll
                for (int h1 = 0; h1 < 8; ++h1) {
                    const float e = __uint_as_float((unsigned int)(unsigned short)evc[s][h1] << 16)
                                    * linv[h1];
                    const float4 po0 = *(const float4*)(&post_s[h1 * 8]);
                    const float4 po1 = *(const float4*)(&post_s[h1 * 8 + 4]);
                    p2[s][0] = fmaf(e, po0.x, p2[s][0]);
                    p2[s][1] = fmaf(e, po0.y, p2[s][1]);
                    p2[s][2] = fmaf(e, po0.z, p2[s][2]);
                    p2[s][3] = fmaf(e, po0.w, p2[s][3]);
                    p2[s][4] = fmaf(e, po1.x, p2[s][4]);
                    p2[s][5] = fmaf(e, po1.y, p2[s][5]);
                    p2[s][6] = fmaf(e, po1.z, p2[s][6]);
                    p2[s][7] = fmaf(e, po1.w, p2[s][7]);
                }
            }
        }
        const int buf = n & 1;
#pragma unroll
        for (int h2 = 0; h2 < 8; ++h2)
            *(unsigned int*)(&p2s[buf][h2][i_p][jj * 2]) = pk2bf(p2[0][h2], p2[1][h2]);
        __syncthreads();

        int jbv = jw0 + quad * 8;
        if (jbv > J - 8) jbv = J - 8;
#pragma unroll
        for (int h2 = 0; h2 < 8; ++h2) {
            const short8 aF = *(const short8*)(&p2s[buf][h2][iL][quad * 8]);
            const short8 bF = *(const short8*)(vt + ((size_t)(b * H + h2) * 64 + dW) * J + jbv);
            y[h2] = __builtin_amdgcn_mfma_f32_16x16x32_bf16(aF, bF, y[h2], 0, 0, 0);
        }
        evc[0] = evn[0]; evc[1] = evn[1];
    }

#pragma unroll
    for (int h2 = 0; h2 < 8; ++h2) {
#pragma unroll
        for (int r = 0; r < 4; ++r) {
            const int ii = i0 + quad * 4 + r;
            atomicAdd(ao + ((size_t)b * N + ii) * DIM + h2 * 64 + dW, y[h2][r]);
        }
    }
}

// ---------------- K2b': pv pass, atomic-free (packed psum stores) ---------
__global__ __launch_bounds__(256)
void attn_pv2_nb(const unsigned short* __restrict__ e16, const unsigned short* __restrict__ vt,
                 const float* __restrict__ postp, const float* __restrict__ hsp,
                 const float* __restrict__ lbuf, float* __restrict__ psum)
{
    const int c = blockIdx.x, tt = 127 - blockIdx.y, b = blockIdx.z;
    const int i0 = tt * 16;
    const int jlim = i0 + 32;
    const int jstart = c * CHUNK;
    if (jstart >= jlim) return;
    const int jend = min(jstart + CHUNK, jlim);
    const int nw = (jend - jstart + 31) >> 5;

    __shared__ __align__(16) unsigned short p2s[2][8][16][40];
    __shared__ __align__(16) float post_s[64];

    const int t = threadIdx.x;
    if (t < 64) post_s[t] = postp[t] * hsp[t & 7];

    const int lane = t & 63, w = t >> 6;
    const int iL = lane & 15, quad = lane >> 4;
    const int dW = w * 16 + iL;
    const int i_p = t & 15;
    const int jj = t >> 4;
    const size_t ebase = (size_t)b * EPB + (size_t)(8 * tt * tt + 24 * tt) * 128;

    float linv[8];
#pragma unroll
    for (int h1 = 0; h1 < 8; ++h1)
        linv[h1] = 1.0f / lbuf[((size_t)(b * 128 + tt) * 8 + h1) * 16 + i_p];

    floatx4 y[8];
#pragma unroll
    for (int h2 = 0; h2 < 8; ++h2) y[h2] = (floatx4){0.f, 0.f, 0.f, 0.f};

    ushortx8 evc[2], evn[2];
    {
        const int j0c = jstart + jj * 2;
        const int ja = min(j0c, jend - 1), jb2 = min(j0c + 1, jend - 1);
        evc[0] = *(const ushortx8*)(e16 + ebase + (size_t)(ja * 16 + i_p) * 8);
        evc[1] = *(const ushortx8*)(e16 + ebase + (size_t)(jb2 * 16 + i_p) * 8);
    }
    __syncthreads();

    for (int n = 0; n < nw; ++n) {
        const int jw0 = jstart + n * 32;
        {
            const int j0n = jstart + (n + 1) * 32 + jj * 2;
            const int ja = min(j0n, jend - 1), jb2 = min(j0n + 1, jend - 1);
            evn[0] = *(const ushortx8*)(e16 + ebase + (size_t)(ja * 16 + i_p) * 8);
            evn[1] = *(const ushortx8*)(e16 + ebase + (size_t)(jb2 * 16 + i_p) * 8);
        }
        float p2[2][8];
#pragma unroll
        for (int s = 0; s < 2; ++s) {
#pragma unroll
            for (int h2 = 0; h2 < 8; ++h2) p2[s][h2] = 0.f;
            const int j = jw0 + jj * 2 + s;
            if (j < jend) {
#pragma unroll
                for (int h1 = 0; h1 < 8; ++h1) {
                    const float e = __uint_as_float((unsigned int)(unsigned short)evc[s][h1] << 16)
                                    * linv[h1];
                    const float4 po0 = *(const float4*)(&post_s[h1 * 8]);
                    const float4 po1 = *(const float4*)(&post_s[h1 * 8 + 4]);
                    p2[s][0] = fmaf(e, po0.x, p2[s][0]);
                    p2[s][1] = fmaf(e, po0.y, p2[s][1]);
                    p2[s][2] = fmaf(e, po0.z, p2[s][2]);
                    p2[s][3] = fmaf(e, po0.w, p2[s][3]);
                    p2[s][4] = fmaf(e, po1.x, p2[s][4]);
                    p2[s][5] = fmaf(e, po1.y, p2[s][5]);
                    p2[s][6] = fmaf(e, po1.z, p2[s][6]);
                    p2[s][7] = fmaf(e, po1.w, p2[s][7]);
                }
            }
        }
        const int buf = n & 1;
#pragma unroll
        for (int h2 = 0; h2 < 8; ++h2)
            *(unsigned int*)(&p2s[buf][h2][i_p][jj * 2]) = pk2bf(p2[0][h2], p2[1][h2]);
        __syncthreads();

        int jbv = jw0 + quad * 8;
        if (jbv > J - 8) jbv = J - 8;
#pragma unroll
        for (int h2 = 0; h2 < 8; ++h2) {
            const short8 aF = *(const short8*)(&p2s[buf][h2][iL][quad * 8]);
            const short8 bF = *(const short8*)(vt + ((size_t)(b * H + h2) * 64 + dW) * J + jbv);
            y[h2] = __builtin_amdgcn_mfma_f32_16x16x32_bf16(aF, bF, y[h2], 0, 0, 0);
        }
        evc[0] = evn[0]; evc[1] = evn[1];
    }

    // packed partial store (plain, no atomics): slot = b*NSLOT + cbase(tt) + c
    int cb = 0;
    for (int t2 = 0; t2 < tt; ++t2) cb += (16 * t2 + 287) >> 8;
    float* pdst = psum + (size_t)(b * NSLOT + cb + c) * 16 * 512;
#pragma unroll
    for (int h2 = 0; h2 < 8; ++h2) {
#pragma unroll
        for (int r = 0; r < 4; ++r)
            pdst[(size_t)(quad * 4 + r) * 512 + h2 * 64 + dW] = y[h2][r];
    }
}

// ---------------- K2c: reduce psum slots -> ao ---------------------------
__global__ __launch_bounds__(256)
void psum_reduce(const float* __restrict__ psum, float* __restrict__ ao)
{
    const int tt = blockIdx.x, b = blockIdx.y;
    const int nc = (16 * tt + 287) >> 8;
    int cb = 0;
    for (int t2 = 0; t2 < tt; ++t2) cb += (16 * t2 + 287) >> 8;
    const float* src = psum + (size_t)(b * NSLOT + cb) * 16 * 512;
    float* dst = ao + ((size_t)b * N + tt * 16) * 512;
    const int t = threadIdx.x;
#pragma unroll
    for (int k = 0; k < 8; ++k) {
        const int idx = t + k * 256;          // float4 index in [0, 2048)
        float4 s = *(const float4*)(src + (size_t)idx * 4);
        for (int cc = 1; cc < nc; ++cc) {
            const float4 v = *(const float4*)(src + (size_t)cc * 8192 + (size_t)idx * 4);
            s.x += v.x; s.y += v.y; s.z += v.z; s.w += v.w;
        }
        *(float4*)(dst + (size_t)idx * 4) = s;
    }
}

// ---------------- K3: output projection GEMM + bias (LDS dbuf, bf16 MFMA) -
__global__ __launch_bounds__(256)
void out_gemm(const float* __restrict__ ain, const unsigned short* __restrict__ WT,
              const float* __restrict__ bo, float* __restrict__ out)
{
    const int t = threadIdx.x;
    const int lane = t & 63, w = t >> 6;
    const int iL = lane & 15, quad = lane >> 4;
    const int mb = blockIdx.x * 64;
    const int n0 = blockIdx.y * 64;

    __shared__ __align__(16) unsigned short As[2][64][32];
    __shared__ __align__(16) unsigned short Bs[2][64][32];

    const int ar0 = t >> 3, as4 = (t & 7) * 4;
    const int br0 = t >> 2, bs8 = (t & 3) * 8;

    floatx4 acc[4];
#pragma unroll
    for (int ng = 0; ng < 4; ++ng) acc[ng] = (floatx4){0.f, 0.f, 0.f, 0.f};

    {
        const float4 v0 = *(const float4*)(ain + (size_t)(mb + ar0) * DIM + as4);
        const float4 v1 = *(const float4*)(ain + (size_t)(mb + ar0 + 32) * DIM + as4);
        ushortx4 o0 = { f2bf(v0.x), f2bf(v0.y), f2bf(v0.z), f2bf(v0.w) };
        ushortx4 o1 = { f2bf(v1.x), f2bf(v1.y), f2bf(v1.z), f2bf(v1.w) };
        *(ushortx4*)(&As[0][ar0][as4]) = o0;
        *(ushortx4*)(&As[0][ar0 + 32][as4]) = o1;
        *(ushortx8*)(&Bs[0][br0][bs8]) =
            *(const ushortx8*)(WT + (size_t)(n0 + br0) * DIM + bs8);
    }
    __syncthreads();

#pragma unroll
    for (int it = 0; it < 16; ++it) {
        const int buf = it & 1;
        if (it + 1 < 16) {
            const int k0 = (it + 1) * 32;
            const float4 v0 = *(const float4*)(ain + (size_t)(mb + ar0) * DIM + k0 + as4);
            const float4 v1 = *(const float4*)(ain + (size_t)(mb + ar0 + 32) * DIM + k0 + as4);
            const ushortx8 bv =
                *(const ushortx8*)(WT + (size_t)(n0 + br0) * DIM + k0 + bs8);
            ushortx4 o0 = { f2bf(v0.x), f2bf(v0.y), f2bf(v0.z), f2bf(v0.w) };
            ushortx4 o1 = { f2bf(v1.x), f2bf(v1.y), f2bf(v1.z), f2bf(v1.w) };
            *(ushortx4*)(&As[buf ^ 1][ar0][as4]) = o0;
            *(ushortx4*)(&As[buf ^ 1][ar0 + 32][as4]) = o1;
            *(ushortx8*)(&Bs[buf ^ 1][br0][bs8]) = bv;
        }
        const short8 af = *(const short8*)(&As[buf][w * 16 + iL][quad * 8]);
#pragma unroll
        for (int ng = 0; ng < 4; ++ng) {
            const short8 bf = *(const short8*)(&Bs[buf][ng * 16 + iL][quad * 8]);
            acc[ng] = __builtin_amdgcn_mfma_f32_16x16x32_bf16(af, bf, acc[ng], 0, 0, 0);
        }
        __syncthreads();
    }

    const int mbw = mb + w * 16;
#pragma unroll
    for (int ng = 0; ng < 4; ++ng) {
        const int n = n0 + ng * 16 + iL;
        const float bias = bo[n];
#pragma unroll
        for (int r = 0; r < 4; ++r) {
            const int m = mbw + quad * 4 + r;
            out[(size_t)m * DIM + n] = acc[ng][r] + bias;
        }
    }
}

extern "C" void kernel_launch(void* const* d_in, const int* in_sizes, int n_in,
                              void* d_out, int out_size, void* d_ws, size_t ws_size,
                              hipStream_t stream)
{
    (void)in_sizes; (void)n_in; (void)out_size;
    const float* x      = (const float*)d_in[0];
    const float* Wq     = (const float*)d_in[1];
    const float* Wk     = (const float*)d_in[2];
    const float* Wv     = (const float*)d_in[3];
    const float* mem_k  = (const float*)d_in[4];
    const float* mem_v  = (const float*)d_in[5];
    const float* pre_p  = (const float*)d_in[6];
    const float* post_p = (const float*)d_in[7];
    const float* hs     = (const float*)d_in[8];
    const float* Wo     = (const float*)d_in[9];
    const float* bo     = (const float*)d_in[10];
    float* out = (float*)d_out;

    constexpr size_t NAO  = (size_t)B * N * DIM;        // 2,097,152 f32
    constexpr size_t NLB  = (size_t)B * 128 * H * 16;   //    32,768 f32
    constexpr size_t NW   = (size_t)DIM * DIM;          //   262,144 u16 each
    constexpr size_t NQ   = (size_t)B * H * N * 64;     // 2,097,152 u16
    constexpr size_t NK   = (size_t)B * H * J * 64;     // 2,113,536 u16
    constexpr size_t NPS  = (size_t)B * NSLOT * 16 * 512;  // psum f32

    float* ws = (float*)d_ws;
    float* ao   = ws;
    float* lbuf = ao + NAO;
    unsigned short* wtq  = (unsigned short*)(lbuf + NLB);
    unsigned short* wtk  = wtq + NW;
    unsigned short* wtv  = wtk + NW;
    unsigned short* wto  = wtv + NW;
    unsigned short* q16  = wto + NW;
    unsigned short* k16  = q16 + NQ;
    unsigned short* v16  = k16 + NK;
    unsigned short* e16  = v16 + NK;
    float* psum = (float*)(e16 + 2 * EPB);

    const size_t needed = ((char*)(psum + NPS)) - ((char*)d_ws);
    const bool use_nb = ws_size >= needed;

    wt_conv<<<dim3(8, 8, 4), 256, 0, stream>>>(Wq, Wk, Wv, Wo, wtq, wtk, wtv, wto);
    qkv_gemm<<<dim3(64, 8, 3), 256, 0, stream>>>(x, wtq, wtk, wtv, q16, k16, v16);
    memkv_copy<<<dim3(32), 256, 0, stream>>>(mem_k, mem_v, k16, v16);
    hipMemsetAsync(ao, 0, (NAO + NLB) * sizeof(float), stream);
    attn_scores<<<dim3(CMAX, 128, B), 256, 0, stream>>>(q16, k16, pre_p, lbuf, e16);
    if (use_nb) {
        attn_pv2_nb<<<dim3(CMAX, 128, B), 256, 0, stream>>>(e16, v16, post_p, hs, lbuf, psum);
        psum_reduce<<<dim3(128, B), 256, 0, stream>>>(psum, ao);
    } else {
        attn_pv2<<<dim3(CMAX, 128, B), 256, 0, stream>>>(e16, v16, post_p, hs, lbuf, ao);
    }
    out_gemm<<<dim3(64, 8), 256, 0, stream>>>(ao, wto, bo, out);
}